// Round 10
// baseline (158.875 us; speedup 1.0000x reference)
//
#include <hip/hip_runtime.h>

// Problem constants (match reference)
#define NE_    1000          // number of energies (evl)
#define RN_    10000         // number of radial grid points
#define NI_    (RN_ - 1)     // 9999 integration intervals
#define CH_    10            // intervals per output chunk (K2)
#define NCH_   1000          // chunks
#define TPC_   64            // slots (threads) per channel in K1
#define LSEG_  160           // intervals per slot = 16 chunks (aligned!)
#define CPB_   4             // channels per block in K1 (250 blocks -> all CUs)

__device__ __forceinline__ float rcpf(float x) { return __builtin_amdgcn_rcpf(x); }

// Substep schedule (p < 64 only). RK4 local error ~ (w*h)^5/120.
__device__ __forceinline__ void substeps_for(int p, int& S, float& invS) {
    if (p < 16)      { S = 4; invS = 0.25f; }
    else if (p < 64) { S = 2; invS = 0.5f;  }
    else             { S = 1; invS = 1.0f;  }
}

// One classic RK4 step for NV independent solutions of a'=b, b'=q(t)a.
template <int NV>
__device__ __forceinline__ void rk4_step(float q1, float q2, float q3,
                                         float h2, float h, float h6,
                                         float a[NV], float b[NV]) {
#pragma unroll
    for (int v = 0; v < NV; ++v) {
        const float ya = a[v], yb = b[v];
        const float k1a = yb;                const float k1b = q1 * ya;
        const float y2a = fmaf(h2, k1a, ya); const float y2b = fmaf(h2, k1b, yb);
        const float k2a = y2b;               const float k2b = q2 * y2a;
        const float y3a = fmaf(h2, k2a, ya); const float y3b = fmaf(h2, k2b, yb);
        const float k3a = y3b;               const float k3b = q2 * y3a;
        const float y4a = fmaf(h,  k3a, ya); const float y4b = fmaf(h,  k3b, yb);
        const float k4a = y4b;               const float k4b = q3 * y4a;
        a[v] = fmaf(h6, fmaf(2.0f, k2a + k3a, k1a + k4a), ya);
        b[v] = fmaf(h6, fmaf(2.0f, k2b + k3b, k1b + k4b), yb);
    }
}

// General (sub-stepped) interval advance — p < 64 and ragged tails only.
template <int NV>
__device__ __forceinline__ void advance_interval(float ta, float tb, float e,
                                                 int S, float invS,
                                                 float a[NV], float b[NV]) {
    const float hs = (tb - ta) * invS;
    const float h2 = 0.5f * hs;
    const float h6 = hs * (1.0f / 6.0f);
    for (int j = 0; j < S; ++j) {
        const float t0 = ta + hs * (float)j;
        const float q1 = fmaf(-2.0f, rcpf(t0),      -e);
        const float q2 = fmaf(-2.0f, rcpf(t0 + h2), -e);
        const float q3 = fmaf(-2.0f, rcpf(t0 + hs), -e);
        rk4_step<NV>(q1, q2, q3, h2, hs, h6, a, b);
    }
}

// Advance NV solutions across [p0, p1) using: general path for p<64,
// DOUBLE RK4 steps (h = 2*grid step, q reused) elsewhere, single-step tail.
// If YST != nullptr, write state to YST[(p/10)*NE_+ei] at every p%10==0.
// All region boundaries (64, slot starts 160j, chunk starts 10c) are even,
// so double-stepping always lands exactly on chunk starts.
template <int NV>
__device__ __forceinline__ void advance_range(int p0, int p1, float step,
                                              float t0g, float e,
                                              float a[NV], float b[NV],
                                              float2* __restrict__ YST, int ei) {
    int p = p0;
    while (p < p1 && p < 64) {                 // only slot 0 enters here
        if (YST && p % CH_ == 0)
            YST[(size_t)(p / CH_) * NE_ + ei] = make_float2(a[0], b[0]);
        const float ta = fmaf((float)p,       step, t0g);
        const float tb = fmaf((float)(p + 1), step, t0g);
        int S; float invS; substeps_for(p, S, invS);
        advance_interval<NV>(ta, tb, e, S, invS, a, b);
        ++p;
    }
    if (p < p1) {
        float tcur = fmaf((float)p, step, t0g);
        float qcur = fmaf(-2.0f, rcpf(tcur), -e);
        while (p + 2 <= p1) {                  // double steps
            if (YST && p % CH_ == 0)
                YST[(size_t)(p / CH_) * NE_ + ei] = make_float2(a[0], b[0]);
            const float tmid  = fmaf((float)(p + 1), step, t0g);
            const float tnext = fmaf((float)(p + 2), step, t0g);
            const float h  = tnext - tcur;
            const float h2 = 0.5f * h;
            const float h6 = h * (1.0f / 6.0f);
            const float qmid  = fmaf(-2.0f, rcpf(tmid),  -e);
            const float qnext = fmaf(-2.0f, rcpf(tnext), -e);
            rk4_step<NV>(qcur, qmid, qnext, h2, h, h6, a, b);
            tcur = tnext; qcur = qnext; p += 2;
        }
        if (p < p1) {                          // odd single-step tail
            if (YST && p % CH_ == 0)
                YST[(size_t)(p / CH_) * NE_ + ei] = make_float2(a[0], b[0]);
            const float tmid  = fmaf((float)p + 0.5f, step, t0g);
            const float tnext = fmaf((float)(p + 1),  step, t0g);
            const float h  = tnext - tcur;
            const float h2 = 0.5f * h;
            const float h6 = h * (1.0f / 6.0f);
            const float qmid  = fmaf(-2.0f, rcpf(tmid),  -e);
            const float qnext = fmaf(-2.0f, rcpf(tnext), -e);
            rk4_step<NV>(qcur, qmid, qnext, h2, h, h6, a, b);
        }
    }
}

// K1: fused propagator + scan + chunk-start emission. Block = 4 ch x 64 slots.
// Phase A: sequential 2x2 basis composite per slot (4-reg state, NO array).
// LDS scan: 64 composites chained per channel (batched-8 LDS reads).
// Phase B: RECOMPUTE the NV=1 integration from the slot-start state, writing
// Yst[c] at each chunk start. Peak live regs ~40 -> no spill possible.
__global__ __launch_bounds__(CPB_ * TPC_) void
k_scanfused(const float* __restrict__ evl, const float* __restrict__ t,
            float2* __restrict__ Yst) {
    __shared__ float4 lm[CPB_][TPC_];   // slot composites {m00,m10,m01,m11}
    __shared__ float2 ly[CPB_][TPC_];   // slot-start states

    const int tid = threadIdx.x;
    const int eil = tid & (CPB_ - 1);
    const int j   = tid / CPB_;                  // slot 0..63
    const int ei  = blockIdx.x * CPB_ + eil;     // 250*4 == NE_

    const float e    = evl[ei];
    const float t0g  = t[0];
    const float step = (t[RN_ - 1] - t0g) * (1.0f / (float)NI_);
    const int p0 = j * LSEG_;
    const int p1 = min(p0 + LSEG_, NI_);         // slot 62 ragged (79), 63 empty

    // ---- phase A: basis propagator over the slot ----
    float a2[2] = {1.0f, 0.0f};
    float b2[2] = {0.0f, 1.0f};
    if (p0 < p1)
        advance_range<2>(p0, p1, step, t0g, e, a2, b2, nullptr, ei);
    lm[eil][j] = make_float4(a2[0], b2[0], a2[1], b2[1]);
    __syncthreads();

    // ---- per-channel serial chain over 64 slot composites (4 threads) ----
    if (j == 0) {
        float ya = 0.0f, yb = 1.0f;              // y(t[0]) = [0, 1]
        for (int c0 = 0; c0 < TPC_; c0 += 8) {
            float4 mm[8];
#pragma unroll
            for (int k = 0; k < 8; ++k) mm[k] = lm[eil][c0 + k];
#pragma unroll
            for (int k = 0; k < 8; ++k) {
                ly[eil][c0 + k] = make_float2(ya, yb);
                const float na = fmaf(mm[k].x, ya, mm[k].z * yb);
                const float nb = fmaf(mm[k].y, ya, mm[k].w * yb);
                ya = na; yb = nb;
            }
        }
    }
    __syncthreads();

    // ---- phase B: re-integrate NV=1 from slot-start, emit chunk starts ----
    const float2 y0 = ly[eil][j];
    float a1[1] = {y0.x};
    float b1[1] = {y0.y};
    if (p0 < p1)
        advance_range<1>(p0, p1, step, t0g, e, a1, b1, Yst, ei);
}

// K2: per (chunk, energy): re-integrate from chunk-start state, one RK4 per
// interval (2 rcp via q reuse), writing [u, u'] at each grid point.
// 1M threads; lane-consecutive ei -> fully coalesced 512B stores.
__global__ void k_out(const float* __restrict__ evl, const float* __restrict__ t,
                      const float2* __restrict__ Yst, float2* __restrict__ out) {
    const int tid = blockIdx.x * blockDim.x + threadIdx.x;
    if (tid >= NE_ * NCH_) return;
    const int ei = tid % NE_;
    const int c  = tid / NE_;
    const float e    = evl[ei];
    const float t0g  = t[0];
    const float step = (t[RN_ - 1] - t0g) * (1.0f / (float)NI_);
    const int p0 = c * CH_;
    const int p1 = min(p0 + CH_, NI_);
    const float2 y0 = Yst[tid];
    float a[1] = {y0.x};
    float b[1] = {y0.y};
    if (c == 0) out[ei] = make_float2(0.0f, 1.0f);   // IC at t[0]
    if (p0 >= 64 && p0 + CH_ == p1) {
        float tcur = fmaf((float)p0, step, t0g);
        float qcur = fmaf(-2.0f, rcpf(tcur), -e);
#pragma unroll
        for (int k = 0; k < CH_; ++k) {
            const float pf    = (float)(p0 + k);
            const float tmid  = fmaf(pf + 0.5f, step, t0g);
            const float tnext = fmaf(pf + 1.0f, step, t0g);
            const float h  = tnext - tcur;
            const float h2 = 0.5f * h;
            const float h6 = h * (1.0f / 6.0f);
            const float qmid  = fmaf(-2.0f, rcpf(tmid),  -e);
            const float qnext = fmaf(-2.0f, rcpf(tnext), -e);
            rk4_step<1>(qcur, qmid, qnext, h2, h, h6, a, b);
            out[(size_t)(p0 + k + 1) * NE_ + ei] = make_float2(a[0], b[0]);
            tcur = tnext; qcur = qnext;
        }
    } else {
        for (int p = p0; p < p1; ++p) {
            const float ta = fmaf((float)p,       step, t0g);
            const float tb = fmaf((float)(p + 1), step, t0g);
            int S; float invS; substeps_for(p, S, invS);
            advance_interval<1>(ta, tb, e, S, invS, a, b);
            out[(size_t)(p + 1) * NE_ + ei] = make_float2(a[0], b[0]);
        }
    }
}

// Fallback: fully serial per channel (only if ws_size is tiny).
__global__ void k_serial(const float* __restrict__ evl, const float* __restrict__ t,
                         float2* __restrict__ out) {
    const int ei = blockIdx.x * blockDim.x + threadIdx.x;
    if (ei >= NE_) return;
    const float e    = evl[ei];
    const float t0g  = t[0];
    const float step = (t[RN_ - 1] - t0g) * (1.0f / (float)NI_);
    float a[1] = {0.0f};
    float b[1] = {1.0f};
    out[ei] = make_float2(0.0f, 1.0f);
    for (int p = 0; p < NI_; ++p) {
        const float ta = fmaf((float)p,       step, t0g);
        const float tb = fmaf((float)(p + 1), step, t0g);
        int S; float invS; substeps_for(p, S, invS);
        advance_interval<1>(ta, tb, e, S, invS, a, b);
        out[(size_t)(p + 1) * NE_ + ei] = make_float2(a[0], b[0]);
    }
}

extern "C" void kernel_launch(void* const* d_in, const int* in_sizes, int n_in,
                              void* d_out, int out_size, void* d_ws, size_t ws_size,
                              hipStream_t stream) {
    const float* evl = (const float*)d_in[0];   // NE_ energies
    const float* t   = (const float*)d_in[1];   // RN_ radial grid
    float2* out = (float2*)d_out;               // [RN_][NE_] of {rad, rad_d}

    const size_t needYst = (size_t)NCH_ * NE_ * sizeof(float2);   // 8 MB
    if (ws_size < needYst) {
        k_serial<<<(NE_ + 255) / 256, 256, 0, stream>>>(evl, t, out);
        return;
    }
    float2* Yst = (float2*)d_ws;

    // K1: 250 blocks x 256 threads (4 channels x 64 slots) -> ~1 wave/SIMD
    k_scanfused<<<NE_ / CPB_, CPB_ * TPC_, 0, stream>>>(evl, t, Yst);
    // K2: 1M threads, coalesced writer
    const int ntask = NE_ * NCH_;
    k_out<<<(ntask + 255) / 256, 256, 0, stream>>>(evl, t, Yst, out);
}

// Round 13
// 117.056 us; speedup vs baseline: 1.3573x; 1.3573x over previous
//
#include <hip/hip_runtime.h>

// Problem constants (match reference)
#define NE_  1000            // number of energies (evl)
#define RN_  10000           // number of radial grid points
#define NI_  (RN_ - 1)       // 9999 integration intervals
#define CH_  10              // intervals per chunk
#define NCH_ 1000            // chunks (chunk 999 ragged: 9 intervals)
#define GL_  25              // chunks per scan group
#define GG_  40              // scan groups (GL_*GG_ == NCH_)

__device__ __forceinline__ float rcpf(float x) { return __builtin_amdgcn_rcpf(x); }

// Substep schedule (general path, p < 64 only). RK4 local error ~ (w*h)^5/120.
__device__ __forceinline__ void substeps_for(int p, int& S, float& invS) {
    if (p < 16)      { S = 4; invS = 0.25f; }
    else if (p < 64) { S = 2; invS = 0.5f;  }
    else             { S = 1; invS = 1.0f;  }
}

// One classic RK4 step for NV independent solutions of a'=b, b'=q(t)a.
template <int NV>
__device__ __forceinline__ void rk4_step(float q1, float q2, float q3,
                                         float h2, float h, float h6,
                                         float a[NV], float b[NV]) {
#pragma unroll
    for (int v = 0; v < NV; ++v) {
        const float ya = a[v], yb = b[v];
        const float k1a = yb;                const float k1b = q1 * ya;
        const float y2a = fmaf(h2, k1a, ya); const float y2b = fmaf(h2, k1b, yb);
        const float k2a = y2b;               const float k2b = q2 * y2a;
        const float y3a = fmaf(h2, k2a, ya); const float y3b = fmaf(h2, k2b, yb);
        const float k3a = y3b;               const float k3b = q2 * y3a;
        const float y4a = fmaf(h,  k3a, ya); const float y4b = fmaf(h,  k3b, yb);
        const float k4a = y4b;               const float k4b = q3 * y4a;
        a[v] = fmaf(h6, fmaf(2.0f, k2a + k3a, k1a + k4a), ya);
        b[v] = fmaf(h6, fmaf(2.0f, k2b + k3b, k1b + k4b), yb);
    }
}

// General (sub-stepped) interval advance — p < 64 and ragged tail only.
template <int NV>
__device__ __forceinline__ void advance_interval(float ta, float tb, float e,
                                                 int S, float invS,
                                                 float a[NV], float b[NV]) {
    const float hs = (tb - ta) * invS;
    const float h2 = 0.5f * hs;
    const float h6 = hs * (1.0f / 6.0f);
    for (int j = 0; j < S; ++j) {
        const float t0 = ta + hs * (float)j;
        const float q1 = fmaf(-2.0f, rcpf(t0),      -e);
        const float q2 = fmaf(-2.0f, rcpf(t0 + h2), -e);
        const float q3 = fmaf(-2.0f, rcpf(t0 + hs), -e);
        rk4_step<NV>(q1, q2, q3, h2, hs, h6, a, b);
    }
}

// K1: per (chunk c, energy e): chunk propagator (2 basis columns).
// Fast path (p0>=64, full chunk): {4,4,2}-interval RK4 steps (3 steps, q
// reused at boundaries). Phase-error arithmetic: wh <= 0.13 -> accumulated
// ~7e-4 relative worst case, vs 5.4x threshold margin. Observed absmax has
// been invariant to step-size changes (reference-discrepancy dominated).
__global__ void k_prop(const float* __restrict__ evl, const float* __restrict__ t,
                       float4* __restrict__ M) {
    const int tid = blockIdx.x * blockDim.x + threadIdx.x;
    if (tid >= NE_ * NCH_) return;
    const int ei = tid % NE_;
    const int c  = tid / NE_;
    const float e    = evl[ei];
    const float t0g  = t[0];
    const float step = (t[RN_ - 1] - t0g) * (1.0f / (float)NI_);
    const int p0 = c * CH_;
    const int p1 = min(p0 + CH_, NI_);
    float a[2] = {1.0f, 0.0f};
    float b[2] = {0.0f, 1.0f};
    if (p0 >= 64 && p0 + CH_ == p1) {
        float tcur = fmaf((float)p0, step, t0g);
        float qcur = fmaf(-2.0f, rcpf(tcur), -e);
        int p = p0;
        const int widths[3] = {4, 4, 2};
#pragma unroll
        for (int s = 0; s < 3; ++s) {
            const int w = widths[s];
            const float tmid  = fmaf((float)(p + w / 2), step, t0g);
            const float tnext = fmaf((float)(p + w),     step, t0g);
            const float h  = tnext - tcur;
            const float h2 = 0.5f * h;
            const float h6 = h * (1.0f / 6.0f);
            const float qmid  = fmaf(-2.0f, rcpf(tmid),  -e);
            const float qnext = fmaf(-2.0f, rcpf(tnext), -e);
            rk4_step<2>(qcur, qmid, qnext, h2, h, h6, a, b);
            tcur = tnext; qcur = qnext; p += w;
        }
    } else {
        for (int p = p0; p < p1; ++p) {
            const float ta = fmaf((float)p,       step, t0g);
            const float tb = fmaf((float)(p + 1), step, t0g);
            int S; float invS; substeps_for(p, S, invS);
            advance_interval<2>(ta, tb, e, S, invS, a, b);
        }
    }
    M[tid] = make_float4(a[0], b[0], a[1], b[1]);   // M[c*NE_+ei]
}

// 2x2 matmul, column-major float4 {m00, m10, m01, m11}. Returns B*A.
__device__ __forceinline__ float4 mmul(float4 B, float4 A) {
    float4 r;
    r.x = fmaf(B.x, A.x, B.z * A.y);
    r.y = fmaf(B.y, A.x, B.w * A.y);
    r.z = fmaf(B.x, A.z, B.z * A.w);
    r.w = fmaf(B.y, A.z, B.w * A.w);
    return r;
}

// Scan phase B1: thread (g, ei) composes the GL_ chunk matrices of group g.
// All loads/stores lane-consecutive in ei -> fully coalesced.
__global__ void k_group(const float4* __restrict__ M, float4* __restrict__ Mg) {
    const int tid = blockIdx.x * blockDim.x + threadIdx.x;
    if (tid >= NE_ * GG_) return;
    const int ei = tid % NE_;
    const int g  = tid / NE_;
    float4 m[GL_];
#pragma unroll
    for (int k = 0; k < GL_; ++k)
        m[k] = M[(size_t)(g * GL_ + k) * NE_ + ei];
    float4 C = m[0];
#pragma unroll
    for (int k = 1; k < GL_; ++k) C = mmul(m[k], C);
    Mg[(size_t)g * NE_ + ei] = C;
}

// Scan phase B2+B3 fused: thread (g, ei) chains the <=40 group composites
// (Mg is 640 KB, L2-resident, coalesced) to get its group-start state, then
// expands to the GL_ chunk-start states of group g. Coalesced loads/stores.
__global__ void k_expand(const float4* __restrict__ M,
                         const float4* __restrict__ Mg,
                         float2* __restrict__ Yst) {
    const int tid = blockIdx.x * blockDim.x + threadIdx.x;
    if (tid >= NE_ * GG_) return;
    const int ei = tid % NE_;
    const int g  = tid / NE_;

    // chain group composites 0..g-1 (batched loads; extras applied as no-op)
    float ya = 0.0f, yb = 1.0f;            // y(t[0]) = [0, 1]
    for (int j0 = 0; j0 < GG_; j0 += 8) {
        if (j0 >= g) break;
        float4 mm[8];
#pragma unroll
        for (int k = 0; k < 8; ++k)
            mm[k] = Mg[(size_t)(j0 + k) * NE_ + ei];   // j0+k < GG_ (GG_%8==0)
#pragma unroll
        for (int k = 0; k < 8; ++k) {
            if (j0 + k < g) {
                const float na = fmaf(mm[k].x, ya, mm[k].z * yb);
                const float nb = fmaf(mm[k].y, ya, mm[k].w * yb);
                ya = na; yb = nb;
            }
        }
    }

    // expand own group's chunk-start states
    float4 m[GL_];
#pragma unroll
    for (int k = 0; k < GL_; ++k)
        m[k] = M[(size_t)(g * GL_ + k) * NE_ + ei];
#pragma unroll
    for (int k = 0; k < GL_; ++k) {
        Yst[(size_t)(g * GL_ + k) * NE_ + ei] = make_float2(ya, yb);
        const float na = fmaf(m[k].x, ya, m[k].z * yb);
        const float nb = fmaf(m[k].y, ya, m[k].w * yb);
        ya = na; yb = nb;
    }
}

// K3: per (chunk, energy): re-integrate from chunk-start state, one RK4 per
// interval (2 rcp via q reuse), writing [u, u'] at each grid point.
// 1M threads; lane-consecutive ei -> fully coalesced 512B stores. (proven)
__global__ void k_out(const float* __restrict__ evl, const float* __restrict__ t,
                      const float2* __restrict__ Yst, float2* __restrict__ out) {
    const int tid = blockIdx.x * blockDim.x + threadIdx.x;
    if (tid >= NE_ * NCH_) return;
    const int ei = tid % NE_;
    const int c  = tid / NE_;
    const float e    = evl[ei];
    const float t0g  = t[0];
    const float step = (t[RN_ - 1] - t0g) * (1.0f / (float)NI_);
    const int p0 = c * CH_;
    const int p1 = min(p0 + CH_, NI_);
    const float2 y0 = Yst[tid];
    float a[1] = {y0.x};
    float b[1] = {y0.y};
    if (c == 0) out[ei] = make_float2(0.0f, 1.0f);   // IC at t[0]
    if (p0 >= 64 && p0 + CH_ == p1) {
        float tcur = fmaf((float)p0, step, t0g);
        float qcur = fmaf(-2.0f, rcpf(tcur), -e);
#pragma unroll
        for (int k = 0; k < CH_; ++k) {
            const float pf    = (float)(p0 + k);
            const float tmid  = fmaf(pf + 0.5f, step, t0g);
            const float tnext = fmaf(pf + 1.0f, step, t0g);
            const float h  = tnext - tcur;
            const float h2 = 0.5f * h;
            const float h6 = h * (1.0f / 6.0f);
            const float qmid  = fmaf(-2.0f, rcpf(tmid),  -e);
            const float qnext = fmaf(-2.0f, rcpf(tnext), -e);
            rk4_step<1>(qcur, qmid, qnext, h2, h, h6, a, b);
            out[(size_t)(p0 + k + 1) * NE_ + ei] = make_float2(a[0], b[0]);
            tcur = tnext; qcur = qnext;
        }
    } else {
        for (int p = p0; p < p1; ++p) {
            const float ta = fmaf((float)p,       step, t0g);
            const float tb = fmaf((float)(p + 1), step, t0g);
            int S; float invS; substeps_for(p, S, invS);
            advance_interval<1>(ta, tb, e, S, invS, a, b);
            out[(size_t)(p + 1) * NE_ + ei] = make_float2(a[0], b[0]);
        }
    }
}

// Fallback: fully serial per channel (only if ws_size is tiny).
__global__ void k_serial(const float* __restrict__ evl, const float* __restrict__ t,
                         float2* __restrict__ out) {
    const int ei = blockIdx.x * blockDim.x + threadIdx.x;
    if (ei >= NE_) return;
    const float e    = evl[ei];
    const float t0g  = t[0];
    const float step = (t[RN_ - 1] - t0g) * (1.0f / (float)NI_);
    float a[1] = {0.0f};
    float b[1] = {1.0f};
    out[ei] = make_float2(0.0f, 1.0f);
    for (int p = 0; p < NI_; ++p) {
        const float ta = fmaf((float)p,       step, t0g);
        const float tb = fmaf((float)(p + 1), step, t0g);
        int S; float invS; substeps_for(p, S, invS);
        advance_interval<1>(ta, tb, e, S, invS, a, b);
        out[(size_t)(p + 1) * NE_ + ei] = make_float2(a[0], b[0]);
    }
}

extern "C" void kernel_launch(void* const* d_in, const int* in_sizes, int n_in,
                              void* d_out, int out_size, void* d_ws, size_t ws_size,
                              hipStream_t stream) {
    const float* evl = (const float*)d_in[0];   // NE_ energies
    const float* t   = (const float*)d_in[1];   // RN_ radial grid
    float2* out = (float2*)d_out;               // [RN_][NE_] of {rad, rad_d}

    // ws layout: M (16 MB) | Yst (8 MB) | Mg (640 KB)
    const size_t szM   = (size_t)NCH_ * NE_ * sizeof(float4);
    const size_t szYst = (size_t)NCH_ * NE_ * sizeof(float2);
    const size_t szMg  = (size_t)GG_  * NE_ * sizeof(float4);

    if (ws_size < szM + szYst + szMg) {
        k_serial<<<(NE_ + 255) / 256, 256, 0, stream>>>(evl, t, out);
        return;
    }

    char* p = (char*)d_ws;
    float4* M   = (float4*)p;               p += szM;
    float2* Yst = (float2*)p;               p += szYst;
    float4* Mg  = (float4*)p;

    const int ntask   = NE_ * NCH_;             // 1,000,000
    const int blocks  = (ntask + 255) / 256;    // 3907
    const int gtask   = NE_ * GG_;              // 40,000
    const int gblocks = (gtask + 255) / 256;    // 157

    k_prop<<<blocks, 256, 0, stream>>>(evl, t, M);
    k_group<<<gblocks, 256, 0, stream>>>(M, Mg);
    k_expand<<<gblocks, 256, 0, stream>>>(M, Mg, Yst);
    k_out<<<blocks, 256, 0, stream>>>(evl, t, Yst, out);
}